// Round 1
// baseline (65.452 us; speedup 1.0000x reference)
//
#include <hip/hip_runtime.h>
#include <hip/hip_bf16.h>

// Problem constants (from reference): B=128, C=32, K=128
// out[b,c,i,j] = s[b,c] where
//   s[b,c] = sum_k (u[c,k]+b_row[c]) * (v[c,k]+b_col[c])
//   u[c,k] = sum_i w_row[c,i] * X[b,i,k]   (column dot)
//   v[c,k] = sum_j w_col[c,j] * X[b,k,j]   (row dot)

constexpr int KDIM = 128;
constexpr int CDIM = 32;

// grid = 256 blocks: blockIdx.x = b*2 + chalf  (chalf selects c in [chalf*16, +16))
// block = 256 threads
__global__ __launch_bounds__(256) void compute_s_kernel(
    const float* __restrict__ x,
    const float* __restrict__ w_col, const float* __restrict__ b_col,
    const float* __restrict__ w_row, const float* __restrict__ b_row,
    float* __restrict__ s_out)
{
    __shared__ float xs[KDIM][KDIM + 1];   // +1 pad: both row and col reads conflict-free (66 KB)
    __shared__ float wrs[16][KDIM];        // w_row half   (8 KB)
    __shared__ float wcs[16][KDIM];        // w_col half   (8 KB)
    __shared__ float uv[2][16][KDIM];      // u and v results (16 KB)

    const int b   = blockIdx.x >> 1;
    const int ch  = blockIdx.x & 1;
    const int tid = threadIdx.x;

    // ---- stage X_b (64 KB) into padded LDS, coalesced float4 loads ----
    const float4* xsrc = reinterpret_cast<const float4*>(x + (size_t)b * KDIM * KDIM);
    #pragma unroll
    for (int r = 0; r < 16; ++r) {
        const int idx4 = tid + 256 * r;        // 0..4095
        const float4 v = xsrc[idx4];
        const int e   = idx4 << 2;
        const int row = e >> 7;
        const int col = e & 127;
        xs[row][col + 0] = v.x;
        xs[row][col + 1] = v.y;
        xs[row][col + 2] = v.z;
        xs[row][col + 3] = v.w;
    }
    // ---- stage the 16 weight rows for this c-half (512 float4 each) ----
    {
        const float4* wrsrc = reinterpret_cast<const float4*>(w_row + ch * 16 * KDIM);
        const float4* wcsrc = reinterpret_cast<const float4*>(w_col + ch * 16 * KDIM);
        #pragma unroll
        for (int r = 0; r < 2; ++r) {
            const int idx4 = tid + 256 * r;    // 0..511
            reinterpret_cast<float4*>(&wrs[0][0])[idx4] = wrsrc[idx4];
            reinterpret_cast<float4*>(&wcs[0][0])[idx4] = wcsrc[idx4];
        }
    }
    __syncthreads();

    // ---- per-thread: k = tid&127; waves 0-1 compute u (col dots), waves 2-3 compute v (row dots)
    const int k   = tid & 127;
    const int sub = tid >> 7;   // wave-uniform branch

    float acc[16];
    #pragma unroll
    for (int c = 0; c < 16; ++c) acc[c] = 0.0f;

    if (sub == 0) {
        // u[c,k] = sum_i wrs[c][i] * xs[i][k]  — xs column read, conflict-free via pad
        for (int i = 0; i < KDIM; ++i) {
            const float xi = xs[i][k];
            #pragma unroll
            for (int c = 0; c < 16; ++c) acc[c] = fmaf(wrs[c][i], xi, acc[c]);
        }
    } else {
        // v[c,k] = sum_j wcs[c][j] * xs[k][j]  — xs row read, conflict-free via pad
        for (int j = 0; j < KDIM; ++j) {
            const float xj = xs[k][j];
            #pragma unroll
            for (int c = 0; c < 16; ++c) acc[c] = fmaf(wcs[c][j], xj, acc[c]);
        }
    }
    #pragma unroll
    for (int c = 0; c < 16; ++c) uv[sub][c][k] = acc[c];
    __syncthreads();

    // ---- reduce over k: 16 groups of 16 lanes, group g owns c = ch*16 + g ----
    const int g    = tid >> 4;    // 0..15
    const int lane = tid & 15;
    const int cg   = ch * 16 + g;
    const float br = b_row[cg];
    const float bc = b_col[cg];

    float part = 0.0f;
    #pragma unroll
    for (int r = 0; r < 8; ++r) {
        const int kk = lane + 16 * r;
        part += (uv[0][g][kk] + br) * (uv[1][g][kk] + bc);
    }
    #pragma unroll
    for (int off = 8; off; off >>= 1)
        part += __shfl_xor(part, off, 16);

    if (lane == 0) s_out[b * CDIM + cg] = part;
}

// grid = 4096 blocks (one per (b,c) output slab of 16384 floats), block = 256
__global__ __launch_bounds__(256) void bcast_kernel(
    const float* __restrict__ s, float* __restrict__ out)
{
    const int bc = blockIdx.x;
    const float val = s[bc];
    float4 v4;
    v4.x = v4.y = v4.z = v4.w = val;
    float4* o = reinterpret_cast<float4*>(out) + (size_t)bc * 4096;
    #pragma unroll
    for (int r = 0; r < 16; ++r) {
        o[threadIdx.x + 256 * r] = v4;
    }
}

extern "C" void kernel_launch(void* const* d_in, const int* in_sizes, int n_in,
                              void* d_out, int out_size, void* d_ws, size_t ws_size,
                              hipStream_t stream) {
    const float* x     = (const float*)d_in[0];
    const float* w_col = (const float*)d_in[1];
    const float* b_col = (const float*)d_in[2];
    const float* w_row = (const float*)d_in[3];
    const float* b_row = (const float*)d_in[4];
    float* out  = (float*)d_out;
    float* s_ws = (float*)d_ws;   // 4096 floats of scratch

    compute_s_kernel<<<256, 256, 0, stream>>>(x, w_col, b_col, w_row, b_row, s_ws);
    bcast_kernel<<<4096, 256, 0, stream>>>(s_ws, out);
}